// Round 1
// baseline (447.665 us; speedup 1.0000x reference)
//
#include <hip/hip_runtime.h>
#include <stdint.h>

typedef unsigned short u16;
typedef __attribute__((ext_vector_type(8))) short short8;   // 8 bf16 (4 VGPRs)
typedef __attribute__((ext_vector_type(4))) float f32x4;
typedef __attribute__((ext_vector_type(4))) unsigned short u16x4;

#define DEV static __device__ __forceinline__

DEV float bf2f(u16 b) { return __uint_as_float(((uint32_t)b) << 16); }
DEV u16 f2bf(float f) {
  uint32_t u = __float_as_uint(f);
  u += 0x7FFFu + ((u >> 16) & 1u);   // round-to-nearest-even
  return (u16)(u >> 16);
}
DEV void gld16(const u16* gsrc, u16* ldsdst) {
  // async 16B/lane global->LDS; LDS dest = wave-uniform base + lane*16
  __builtin_amdgcn_global_load_lds((const __attribute__((address_space(1))) void*)gsrc,
                                   (__attribute__((address_space(3))) void*)ldsdst, 16, 0, 0);
}
#define MFMA16(a, b, c) __builtin_amdgcn_mfma_f32_16x16x32_bf16(a, b, c, 0, 0, 0)

// ---------------------------------------------------------------------------
// fp32 -> bf16 conversion: x (8192x1024) + Wq,Wk,Wv,Wo (1024x1024 each)
// ---------------------------------------------------------------------------
__global__ __launch_bounds__(256) void k_convert(
    const float* __restrict__ x, const float* __restrict__ wq, const float* __restrict__ wk,
    const float* __restrict__ wv, const float* __restrict__ wo, u16* __restrict__ ws)
{
  int bid = blockIdx.x, t = threadIdx.x;
  const float* src; u16* dst; size_t off;
  if (bid < 8192) { src = x; dst = ws; off = (size_t)bid * 1024; }
  else {
    int r = bid - 8192; int sel = r >> 10; int lb = r & 1023;
    src = sel == 0 ? wq : sel == 1 ? wk : sel == 2 ? wv : wo;
    dst = ws + 8388608u + (size_t)sel * 1048576u;
    off = (size_t)lb * 1024;
  }
  size_t e = off + (size_t)t * 4;
  f32x4 v = *(const f32x4*)(src + e);
  u16x4 o;
  o.x = f2bf(v.x); o.y = f2bf(v.y); o.z = f2bf(v.z); o.w = f2bf(v.w);
  *(u16x4*)(dst + e) = o;
}

// ---------------------------------------------------------------------------
// Shared GEMM main loop: C[m][n] = sum_k A[m][k] * B[n][k]   (both K-inner)
// 128x128 tile, BK=32, 4 waves (2x2), global_load_lds staging with
// XOR-swizzled source so fragment ds_read_b128 are ~2-way (free) conflicts.
// ---------------------------------------------------------------------------
DEV void gemm_mainloop(const u16* __restrict__ A, const u16* __restrict__ B,
                       int m0, int n0, u16* As, u16* Bs, f32x4 acc[4][4])
{
  const int tid = threadIdx.x, lane = tid & 63, w = tid >> 6;
  const int fr = lane & 15, g = lane >> 4;
  const int wm = w >> 1, wn = w & 1;

  // staging: tile is 128 rows x 32 cols bf16 = 8KB = 8 chunks of 1KB (1 per wave-call)
  const int rowA0 = (w * 2 + 0) * 16 + (lane >> 2);
  const int rowA1 = (w * 2 + 1) * 16 + (lane >> 2);
  const int ci = lane & 3;  // 16B chunk within 64B row
  const u16* ga0 = A + (size_t)(m0 + rowA0) * 1024 + ((ci ^ (rowA0 & 3)) << 3);
  const u16* ga1 = A + (size_t)(m0 + rowA1) * 1024 + ((ci ^ (rowA1 & 3)) << 3);
  const u16* gb0 = B + (size_t)(n0 + rowA0) * 1024 + ((ci ^ (rowA0 & 3)) << 3);
  const u16* gb1 = B + (size_t)(n0 + rowA1) * 1024 + ((ci ^ (rowA1 & 3)) << 3);
  u16* lA0 = As + (w * 2 + 0) * 512;
  u16* lA1 = As + (w * 2 + 1) * 512;
  u16* lB0 = Bs + (w * 2 + 0) * 512;
  u16* lB1 = Bs + (w * 2 + 1) * 512;

  int raf[4], rbf[4];
#pragma unroll
  for (int i = 0; i < 4; ++i) {
    int rA = wm * 64 + i * 16 + fr;
    raf[i] = rA * 32 + ((g ^ (rA & 3)) << 3);
    int rB = wn * 64 + i * 16 + fr;
    rbf[i] = rB * 32 + ((g ^ (rB & 3)) << 3);
  }

  for (int k0 = 0; k0 < 1024; k0 += 32) {
    __syncthreads();           // previous iter's LDS reads complete
    gld16(ga0 + k0, lA0);
    gld16(ga1 + k0, lA1);
    gld16(gb0 + k0, lB0);
    gld16(gb1 + k0, lB1);
    __syncthreads();           // drains vmcnt: staged data visible
    short8 af[4], bf[4];
#pragma unroll
    for (int i = 0; i < 4; ++i) af[i] = *(const short8*)&As[raf[i]];
#pragma unroll
    for (int i = 0; i < 4; ++i) bf[i] = *(const short8*)&Bs[rbf[i]];
#pragma unroll
    for (int mi = 0; mi < 4; ++mi)
#pragma unroll
      for (int ni = 0; ni < 4; ++ni)
        acc[mi][ni] = MFMA16(af[mi], bf[ni], acc[mi][ni]);
  }
}

// ---------------------------------------------------------------------------
// QKV projection: grid (64, 24); blockIdx.y selects matrix (0..7 Q, 8..15 K, 16..23 V)
// Q written *0.125 (folds 1/sqrt(dk)); Q,K -> [BH][S][64]; V -> transposed [BH][64][S]
// ---------------------------------------------------------------------------
__global__ __launch_bounds__(256) void k_gemm_qkv(
    const u16* __restrict__ xb, const u16* __restrict__ wqb, const u16* __restrict__ wkb,
    const u16* __restrict__ wvb, const float* __restrict__ bq, const float* __restrict__ bk,
    const float* __restrict__ bv, u16* __restrict__ Qg, u16* __restrict__ Kg,
    u16* __restrict__ Vtg)
{
  __shared__ u16 As[128 * 32], Bs[128 * 32];
  const int mb = blockIdx.x, nb_all = blockIdx.y;
  const int mat = nb_all >> 3, nb = nb_all & 7;
  const u16* W = mat == 0 ? wqb : (mat == 1 ? wkb : wvb);
  const float* bias = mat == 0 ? bq : (mat == 1 ? bk : bv);
  const int m0 = mb * 128, n0 = nb * 128;

  f32x4 acc[4][4];
  f32x4 z = {0.f, 0.f, 0.f, 0.f};
#pragma unroll
  for (int i = 0; i < 4; ++i)
#pragma unroll
    for (int j = 0; j < 4; ++j) acc[i][j] = z;

  gemm_mainloop(xb, W, m0, n0, As, Bs, acc);

  const int tid = threadIdx.x, lane = tid & 63, w = tid >> 6;
  const int fr = lane & 15, g = lane >> 4;
  const int wm = w >> 1, wn = w & 1;

  if (mat <= 1) {
    u16* Og = mat == 0 ? Qg : Kg;
    const float scale = mat == 0 ? 0.125f : 1.0f;
#pragma unroll
    for (int mi = 0; mi < 4; ++mi)
#pragma unroll
      for (int ni = 0; ni < 4; ++ni) {
        int n = n0 + wn * 64 + ni * 16 + fr;
        float bv_ = bias[n];
        int h = n >> 6, d = n & 63;
#pragma unroll
        for (int r = 0; r < 4; ++r) {
          int m = m0 + wm * 64 + mi * 16 + 4 * g + r;
          int b = m >> 11, s = m & 2047;
          float v = (acc[mi][ni][r] + bv_) * scale;
          Og[(((size_t)(b * 16 + h)) * 2048 + (size_t)s) * 64 + d] = f2bf(v);
        }
      }
  } else {
#pragma unroll
    for (int mi = 0; mi < 4; ++mi)
#pragma unroll
      for (int ni = 0; ni < 4; ++ni) {
        int n = n0 + wn * 64 + ni * 16 + fr;
        float bv_ = bias[n];
        int h = n >> 6, d = n & 63;
        int mbase = m0 + wm * 64 + mi * 16 + 4 * g;
        int b = mbase >> 11, s0 = mbase & 2047;
        u16x4 pk;
        pk.x = f2bf(acc[mi][ni][0] + bv_);
        pk.y = f2bf(acc[mi][ni][1] + bv_);
        pk.z = f2bf(acc[mi][ni][2] + bv_);
        pk.w = f2bf(acc[mi][ni][3] + bv_);
        *(u16x4*)&Vtg[(((size_t)(b * 16 + h)) * 64 + d) * 2048 + s0] = pk;
      }
  }
}

// ---------------------------------------------------------------------------
// Flash attention. grid (16 qblocks, 64 bh), 256 threads (4 waves x 32 q-rows).
// KV tile = 128. K staged [128][64] swizzled; V staged from transposed global
// [64][128] swizzled -> PV B-frags are contiguous ds_read_b128. Online softmax
// wave-parallel (all 64 lanes active). P transposed via wave-private LDS.
// ---------------------------------------------------------------------------
__global__ __launch_bounds__(256) void k_attn(
    const u16* __restrict__ Qg, const u16* __restrict__ Kg, const u16* __restrict__ Vtg,
    u16* __restrict__ headb)
{
  __shared__ u16 K_lds[128 * 64];     // 16KB
  __shared__ u16 V_lds[64 * 128];     // 16KB
  __shared__ u16 P_lds[4 * 32 * 128]; // 32KB (8KB per wave)
  const int tid = threadIdx.x, lane = tid & 63, w = tid >> 6;
  const int fr = lane & 15, g = lane >> 4;
  const int qb = blockIdx.x, bh = blockIdx.y;
  const u16* Qbase = Qg + (size_t)bh * 2048 * 64;
  const u16* Kbase = Kg + (size_t)bh * 2048 * 64;
  const u16* Vbase = Vtg + (size_t)bh * 64 * 2048;
  u16* Pw = P_lds + w * (32 * 128);

  // Q fragments straight from global (pre-scaled by 0.125 in projection)
  short8 qf[2][2];
#pragma unroll
  for (int mi = 0; mi < 2; ++mi)
#pragma unroll
    for (int kt = 0; kt < 2; ++kt) {
      int qrow = qb * 128 + w * 32 + mi * 16 + fr;
      qf[mi][kt] = *(const short8*)&Qbase[(size_t)qrow * 64 + kt * 32 + g * 8];
    }

  f32x4 po[2][4];
  f32x4 z = {0.f, 0.f, 0.f, 0.f};
#pragma unroll
  for (int mi = 0; mi < 2; ++mi)
#pragma unroll
    for (int dt = 0; dt < 4; ++dt) po[mi][dt] = z;
  float mrun[2][4], lrun[2][4];
#pragma unroll
  for (int mi = 0; mi < 2; ++mi)
#pragma unroll
    for (int r = 0; r < 4; ++r) { mrun[mi][r] = -1e30f; lrun[mi][r] = 0.f; }

  for (int kv = 0; kv < 16; ++kv) {
    __syncthreads();  // everyone done reading K/V from previous tile
    // stage K tile [128][64], rows 128B, chunk-XOR swizzle (row&7)
#pragma unroll
    for (int i = 0; i < 4; ++i) {
      int c = w * 4 + i;
      int row = c * 8 + (lane >> 3);
      int ci = lane & 7;
      gld16(Kbase + ((size_t)(kv * 128 + row)) * 64 + ((ci ^ (row & 7)) << 3), &K_lds[c * 512]);
    }
    // stage V^T tile [64][128], rows 256B, chunk-XOR swizzle (row&7)
#pragma unroll
    for (int i = 0; i < 4; ++i) {
      int c = w * 4 + i;
      int row = c * 4 + (lane >> 4);
      int ci = lane & 15;
      gld16(Vbase + (size_t)row * 2048 + kv * 128 + ((ci ^ (row & 7)) << 3), &V_lds[c * 512]);
    }
    __syncthreads();  // staged data landed

    // S = Q K^T (already includes 1/8 scale via Q)
    f32x4 sc[2][8];
#pragma unroll
    for (int mi = 0; mi < 2; ++mi)
#pragma unroll
      for (int nt = 0; nt < 8; ++nt) sc[mi][nt] = z;
#pragma unroll
    for (int nt = 0; nt < 8; ++nt) {
#pragma unroll
      for (int kt = 0; kt < 2; ++kt) {
        int rk = nt * 16 + fr;
        short8 kb = *(const short8*)&K_lds[rk * 64 + (((kt * 4 + g) ^ (rk & 7)) << 3)];
        sc[0][nt] = MFMA16(qf[0][kt], kb, sc[0][nt]);
        sc[1][nt] = MFMA16(qf[1][kt], kb, sc[1][nt]);
      }
    }

    // online softmax (rows live in (mi,reg); cols in (nt, lane&15))
#pragma unroll
    for (int mi = 0; mi < 2; ++mi) {
#pragma unroll
      for (int r = 0; r < 4; ++r) {
        float mx = sc[mi][0][r];
#pragma unroll
        for (int nt = 1; nt < 8; ++nt) mx = fmaxf(mx, sc[mi][nt][r]);
        mx = fmaxf(mx, __shfl_xor(mx, 1, 64));
        mx = fmaxf(mx, __shfl_xor(mx, 2, 64));
        mx = fmaxf(mx, __shfl_xor(mx, 4, 64));
        mx = fmaxf(mx, __shfl_xor(mx, 8, 64));
        float mnew = fmaxf(mrun[mi][r], mx);
        float alpha = __expf(mrun[mi][r] - mnew);
        float rs = 0.f;
#pragma unroll
        for (int nt = 0; nt < 8; ++nt) {
          float p = __expf(sc[mi][nt][r] - mnew);
          sc[mi][nt][r] = p;
          rs += p;
        }
        rs += __shfl_xor(rs, 1, 64);
        rs += __shfl_xor(rs, 2, 64);
        rs += __shfl_xor(rs, 4, 64);
        rs += __shfl_xor(rs, 8, 64);
        lrun[mi][r] = lrun[mi][r] * alpha + rs;
        mrun[mi][r] = mnew;
#pragma unroll
        for (int dt = 0; dt < 4; ++dt) po[mi][dt][r] *= alpha;
      }
    }

    // transpose P into wave-private LDS (rows 256B, same XOR swizzle)
#pragma unroll
    for (int mi = 0; mi < 2; ++mi)
#pragma unroll
      for (int nt = 0; nt < 8; ++nt)
#pragma unroll
        for (int r = 0; r < 4; ++r) {
          int row = mi * 16 + 4 * g + r;
          int C = nt * 16 + fr;
          Pw[row * 128 + ((((C >> 3) ^ (row & 7)) << 3) | (C & 7))] = f2bf(sc[mi][nt][r]);
        }

    // O += P V  (A-frags from Pw, B-frags from V^T: both contiguous b128)
#pragma unroll
    for (int kt = 0; kt < 4; ++kt) {
      short8 pa[2];
#pragma unroll
      for (int mi = 0; mi < 2; ++mi) {
        int row = mi * 16 + fr;
        pa[mi] = *(const short8*)&Pw[row * 128 + (((kt * 4 + g) ^ (row & 7)) << 3)];
      }
#pragma unroll
      for (int dt = 0; dt < 4; ++dt) {
        int rd = dt * 16 + fr;
        short8 vb = *(const short8*)&V_lds[rd * 128 + (((kt * 4 + g) ^ (rd & 7)) << 3)];
        po[0][dt] = MFMA16(pa[0], vb, po[0][dt]);
        po[1][dt] = MFMA16(pa[1], vb, po[1][dt]);
      }
    }
  }

  // epilogue: head[b][s][h*64+d] = O / l
  const int b = bh >> 4, h = bh & 15;
#pragma unroll
  for (int mi = 0; mi < 2; ++mi)
#pragma unroll
    for (int dt = 0; dt < 4; ++dt)
#pragma unroll
      for (int r = 0; r < 4; ++r) {
        int srow = qb * 128 + w * 32 + mi * 16 + 4 * g + r;
        float v = po[mi][dt][r] / lrun[mi][r];
        int e = h * 64 + dt * 16 + fr;
        headb[((size_t)(b * 2048 + srow)) * 1024 + e] = f2bf(v);
      }
}

// ---------------------------------------------------------------------------
// Output projection: proj = head @ Wo^T + bo  (bf16 out)
// ---------------------------------------------------------------------------
__global__ __launch_bounds__(256) void k_gemm_o(
    const u16* __restrict__ headb, const u16* __restrict__ wob, const float* __restrict__ bo,
    u16* __restrict__ projb)
{
  __shared__ u16 As[128 * 32], Bs[128 * 32];
  const int m0 = blockIdx.x * 128, n0 = blockIdx.y * 128;
  f32x4 acc[4][4];
  f32x4 z = {0.f, 0.f, 0.f, 0.f};
#pragma unroll
  for (int i = 0; i < 4; ++i)
#pragma unroll
    for (int j = 0; j < 4; ++j) acc[i][j] = z;

  gemm_mainloop(headb, wob, m0, n0, As, Bs, acc);

  const int tid = threadIdx.x, lane = tid & 63, w = tid >> 6;
  const int fr = lane & 15, g = lane >> 4;
  const int wm = w >> 1, wn = w & 1;
#pragma unroll
  for (int mi = 0; mi < 4; ++mi)
#pragma unroll
    for (int ni = 0; ni < 4; ++ni) {
      int n = n0 + wn * 64 + ni * 16 + fr;
      float bv_ = bo[n];
#pragma unroll
      for (int r = 0; r < 4; ++r) {
        int m = m0 + wm * 64 + mi * 16 + 4 * g + r;
        projb[(size_t)m * 1024 + n] = f2bf(acc[mi][ni][r] + bv_);
      }
    }
}

// ---------------------------------------------------------------------------
// LayerNorm + residual: out = x + (proj - mu) * rsqrt(var+eps) * gamma + beta
// ---------------------------------------------------------------------------
__global__ __launch_bounds__(256) void k_ln(
    const u16* __restrict__ projb, const float* __restrict__ x,
    const float* __restrict__ gamma, const float* __restrict__ beta, float* __restrict__ out)
{
  __shared__ float sh1[4], sh2[4];
  const int row = blockIdx.x, t = threadIdx.x, lane = t & 63, w = t >> 6;
  const size_t base = (size_t)row * 1024;
  u16x4 pv = *(const u16x4*)&projb[base + t * 4];
  float v0 = bf2f(pv.x), v1 = bf2f(pv.y), v2 = bf2f(pv.z), v3 = bf2f(pv.w);
  float s1 = v0 + v1 + v2 + v3;
  float s2 = v0 * v0 + v1 * v1 + v2 * v2 + v3 * v3;
  for (int m = 1; m < 64; m <<= 1) {
    s1 += __shfl_xor(s1, m, 64);
    s2 += __shfl_xor(s2, m, 64);
  }
  if (lane == 0) { sh1[w] = s1; sh2[w] = s2; }
  __syncthreads();
  s1 = sh1[0] + sh1[1] + sh1[2] + sh1[3];
  s2 = sh2[0] + sh2[1] + sh2[2] + sh2[3];
  float mu = s1 * (1.0f / 1024.0f);
  float var = s2 * (1.0f / 1024.0f) - mu * mu;
  float rsd = rsqrtf(var + 1e-5f);
  f32x4 xv = *(const f32x4*)&x[base + t * 4];
  f32x4 res;
  int e = t * 4;
  res.x = xv.x + (v0 - mu) * rsd * gamma[e + 0] + beta[e + 0];
  res.y = xv.y + (v1 - mu) * rsd * gamma[e + 1] + beta[e + 1];
  res.z = xv.z + (v2 - mu) * rsd * gamma[e + 2] + beta[e + 2];
  res.w = xv.w + (v3 - mu) * rsd * gamma[e + 3] + beta[e + 3];
  *(f32x4*)&out[base + t * 4] = res;
}

// ---------------------------------------------------------------------------
extern "C" void kernel_launch(void* const* d_in, const int* in_sizes, int n_in,
                              void* d_out, int out_size, void* d_ws, size_t ws_size,
                              hipStream_t stream)
{
  const float* x     = (const float*)d_in[0];
  const float* Wq    = (const float*)d_in[1];
  const float* bq    = (const float*)d_in[2];
  const float* Wk    = (const float*)d_in[3];
  const float* bk    = (const float*)d_in[4];
  const float* Wv    = (const float*)d_in[5];
  const float* bv    = (const float*)d_in[6];
  const float* Wo    = (const float*)d_in[7];
  const float* bo    = (const float*)d_in[8];
  const float* gamma = (const float*)d_in[9];
  const float* beta  = (const float*)d_in[10];
  float* out = (float*)d_out;

  u16* ws   = (u16*)d_ws;
  u16* xb   = ws;                    // 8192*1024
  u16* wqb  = ws + 8388608;          // 1024*1024
  u16* wkb  = wqb + 1048576;
  u16* wvb  = wkb + 1048576;
  u16* wob  = wvb + 1048576;
  u16* Qg   = wob + 1048576;         // [64][2048][64]
  u16* Kg   = Qg + 8388608;          // [64][2048][64]
  u16* Vtg  = Kg + 8388608;          // [64][64][2048]
  u16* headb = Vtg + 8388608;        // [8192][1024]
  u16* projb = Qg;                   // reuse Q region (dead after attention)

  k_convert<<<12288, 256, 0, stream>>>(x, Wq, Wk, Wv, Wo, ws);
  k_gemm_qkv<<<dim3(64, 24), 256, 0, stream>>>(xb, wqb, wkb, wvb, bq, bk, bv, Qg, Kg, Vtg);
  k_attn<<<dim3(16, 64), 256, 0, stream>>>(Qg, Kg, Vtg, headb);
  k_gemm_o<<<dim3(64, 8), 256, 0, stream>>>(headb, wob, bo, projb);
  k_ln<<<8192, 256, 0, stream>>>(projb, x, gamma, beta, out);
}

// Round 3
// 239.952 us; speedup vs baseline: 1.8656x; 1.8656x over previous
//
#include <hip/hip_runtime.h>
#include <stdint.h>

typedef unsigned short u16;
typedef unsigned int u32;
typedef __attribute__((ext_vector_type(8))) short short8;   // 8 bf16 (4 VGPRs)
typedef __attribute__((ext_vector_type(4))) short short4b;  // 4 bf16 (2 VGPRs)
typedef __attribute__((ext_vector_type(4))) float f32x4;
typedef __attribute__((ext_vector_type(4))) unsigned short u16x4;

#define DEV static __device__ __forceinline__

DEV float bf2f(u16 b) { return __uint_as_float(((uint32_t)b) << 16); }
DEV u16 f2bf(float f) {
  uint32_t u = __float_as_uint(f);
  u += 0x7FFFu + ((u >> 16) & 1u);   // round-to-nearest-even
  return (u16)(u >> 16);
}
DEV void gld16(const u16* gsrc, u16* ldsdst) {
  __builtin_amdgcn_global_load_lds((const __attribute__((address_space(1))) void*)gsrc,
                                   (__attribute__((address_space(3))) void*)ldsdst, 16, 0, 0);
}
#define MFMA16(a, b, c) __builtin_amdgcn_mfma_f32_16x16x32_bf16(a, b, c, 0, 0, 0)

#if __has_builtin(__builtin_amdgcn_mfma_f32_16x16x16bf16_1k)
DEV f32x4 mfma_k16(short4b a, short4b b, f32x4 c) {
  return __builtin_amdgcn_mfma_f32_16x16x16bf16_1k(a, b, c, 0, 0, 0);
}
#else
DEV f32x4 mfma_k16(short4b a, short4b b, f32x4 c) {
  f32x4 d;
  asm volatile("v_mfma_f32_16x16x16_bf16 %0, %1, %2, %3"
               : "=&v"(d) : "v"(a), "v"(b), "v"(c));
  return d;
}
#endif

#if __has_builtin(__builtin_amdgcn_exp2f)
DEV float fexp2(float x) { return __builtin_amdgcn_exp2f(x); }
#else
DEV float fexp2(float x) { return exp2f(x); }
#endif

DEV u32 cvtpk(float lo, float hi) {
  u32 r;
  asm("v_cvt_pk_bf16_f32 %0, %1, %2" : "=v"(r) : "v"(lo), "v"(hi));
  return r;
}

DEV f32x4 v4max(f32x4 a, f32x4 b) {
  f32x4 r;
  r.x = fmaxf(a.x, b.x); r.y = fmaxf(a.y, b.y);
  r.z = fmaxf(a.z, b.z); r.w = fmaxf(a.w, b.w);
  return r;
}

// ---------------------------------------------------------------------------
// fp32 -> bf16 conversion: x (8192x1024) + Wq,Wk,Wv,Wo (1024x1024 each)
// ---------------------------------------------------------------------------
__global__ __launch_bounds__(256) void k_convert(
    const float* __restrict__ x, const float* __restrict__ wq, const float* __restrict__ wk,
    const float* __restrict__ wv, const float* __restrict__ wo, u16* __restrict__ ws)
{
  int bid = blockIdx.x, t = threadIdx.x;
  const float* src; u16* dst; size_t off;
  if (bid < 8192) { src = x; dst = ws; off = (size_t)bid * 1024; }
  else {
    int r = bid - 8192; int sel = r >> 10; int lb = r & 1023;
    src = sel == 0 ? wq : sel == 1 ? wk : sel == 2 ? wv : wo;
    dst = ws + 8388608u + (size_t)sel * 1048576u;
    off = (size_t)lb * 1024;
  }
  size_t e = off + (size_t)t * 4;
  f32x4 v = *(const f32x4*)(src + e);
  u16x4 o;
  o.x = f2bf(v.x); o.y = f2bf(v.y); o.z = f2bf(v.z); o.w = f2bf(v.w);
  *(u16x4*)(dst + e) = o;
}

// ---------------------------------------------------------------------------
// Shared GEMM main loop (unchanged from R1)
// ---------------------------------------------------------------------------
DEV void gemm_mainloop(const u16* __restrict__ A, const u16* __restrict__ B,
                       int m0, int n0, u16* As, u16* Bs, f32x4 acc[4][4])
{
  const int tid = threadIdx.x, lane = tid & 63, w = tid >> 6;
  const int fr = lane & 15, g = lane >> 4;
  const int wm = w >> 1, wn = w & 1;

  const int rowA0 = (w * 2 + 0) * 16 + (lane >> 2);
  const int rowA1 = (w * 2 + 1) * 16 + (lane >> 2);
  const int ci = lane & 3;
  const u16* ga0 = A + (size_t)(m0 + rowA0) * 1024 + ((ci ^ (rowA0 & 3)) << 3);
  const u16* ga1 = A + (size_t)(m0 + rowA1) * 1024 + ((ci ^ (rowA1 & 3)) << 3);
  const u16* gb0 = B + (size_t)(n0 + rowA0) * 1024 + ((ci ^ (rowA0 & 3)) << 3);
  const u16* gb1 = B + (size_t)(n0 + rowA1) * 1024 + ((ci ^ (rowA1 & 3)) << 3);
  u16* lA0 = As + (w * 2 + 0) * 512;
  u16* lA1 = As + (w * 2 + 1) * 512;
  u16* lB0 = Bs + (w * 2 + 0) * 512;
  u16* lB1 = Bs + (w * 2 + 1) * 512;

  int raf[4], rbf[4];
#pragma unroll
  for (int i = 0; i < 4; ++i) {
    int rA = wm * 64 + i * 16 + fr;
    raf[i] = rA * 32 + ((g ^ (rA & 3)) << 3);
    int rB = wn * 64 + i * 16 + fr;
    rbf[i] = rB * 32 + ((g ^ (rB & 3)) << 3);
  }

  for (int k0 = 0; k0 < 1024; k0 += 32) {
    __syncthreads();
    gld16(ga0 + k0, lA0);
    gld16(ga1 + k0, lA1);
    gld16(gb0 + k0, lB0);
    gld16(gb1 + k0, lB1);
    __syncthreads();
    short8 af[4], bf[4];
#pragma unroll
    for (int i = 0; i < 4; ++i) af[i] = *(const short8*)&As[raf[i]];
#pragma unroll
    for (int i = 0; i < 4; ++i) bf[i] = *(const short8*)&Bs[rbf[i]];
#pragma unroll
    for (int mi = 0; mi < 4; ++mi)
#pragma unroll
      for (int ni = 0; ni < 4; ++ni)
        acc[mi][ni] = MFMA16(af[mi], bf[ni], acc[mi][ni]);
  }
}

// ---------------------------------------------------------------------------
// QKV projection. Q written *0.125*log2(e) (folds attention scale + exp2 domain)
// ---------------------------------------------------------------------------
__global__ __launch_bounds__(256) void k_gemm_qkv(
    const u16* __restrict__ xb, const u16* __restrict__ wqb, const u16* __restrict__ wkb,
    const u16* __restrict__ wvb, const float* __restrict__ bq, const float* __restrict__ bk,
    const float* __restrict__ bv, u16* __restrict__ Qg, u16* __restrict__ Kg,
    u16* __restrict__ Vtg)
{
  __shared__ u16 As[128 * 32], Bs[128 * 32];
  const int mb = blockIdx.x, nb_all = blockIdx.y;
  const int mat = nb_all >> 3, nb = nb_all & 7;
  const u16* W = mat == 0 ? wqb : (mat == 1 ? wkb : wvb);
  const float* bias = mat == 0 ? bq : (mat == 1 ? bk : bv);
  const int m0 = mb * 128, n0 = nb * 128;

  f32x4 acc[4][4];
  f32x4 z = {0.f, 0.f, 0.f, 0.f};
#pragma unroll
  for (int i = 0; i < 4; ++i)
#pragma unroll
    for (int j = 0; j < 4; ++j) acc[i][j] = z;

  gemm_mainloop(xb, W, m0, n0, As, Bs, acc);

  const int tid = threadIdx.x, lane = tid & 63, w = tid >> 6;
  const int fr = lane & 15, g = lane >> 4;
  const int wm = w >> 1, wn = w & 1;

  if (mat <= 1) {
    u16* Og = mat == 0 ? Qg : Kg;
    // 0.125 (1/sqrt(dk)) * log2(e): softmax runs in exp2 domain
    const float scale = mat == 0 ? 0.18033688011112042f : 1.0f;
#pragma unroll
    for (int mi = 0; mi < 4; ++mi)
#pragma unroll
      for (int ni = 0; ni < 4; ++ni) {
        int n = n0 + wn * 64 + ni * 16 + fr;
        float bv_ = bias[n];
        int h = n >> 6, d = n & 63;
#pragma unroll
        for (int r = 0; r < 4; ++r) {
          int m = m0 + wm * 64 + mi * 16 + 4 * g + r;
          int b = m >> 11, s = m & 2047;
          float v = (acc[mi][ni][r] + bv_) * scale;
          Og[(((size_t)(b * 16 + h)) * 2048 + (size_t)s) * 64 + d] = f2bf(v);
        }
      }
  } else {
#pragma unroll
    for (int mi = 0; mi < 4; ++mi)
#pragma unroll
      for (int ni = 0; ni < 4; ++ni) {
        int n = n0 + wn * 64 + ni * 16 + fr;
        float bv_ = bias[n];
        int h = n >> 6, d = n & 63;
        int mbase = m0 + wm * 64 + mi * 16 + 4 * g;
        int b = mbase >> 11, s0 = mbase & 2047;
        u16x4 pk;
        pk.x = f2bf(acc[mi][ni][0] + bv_);
        pk.y = f2bf(acc[mi][ni][1] + bv_);
        pk.z = f2bf(acc[mi][ni][2] + bv_);
        pk.w = f2bf(acc[mi][ni][3] + bv_);
        *(u16x4*)&Vtg[(((size_t)(b * 16 + h)) * 64 + d) * 2048 + s0] = pk;
      }
  }
}

// ---------------------------------------------------------------------------
// Flash attention, swapped-QK^T form. grid (16 qblocks, 64 bh), 4 waves.
// S^T = mfma(K,Q): lane (fr,g) holds S[k=nt*16+4g+r][q=fr] -> softmax is
// register-local. P packs in-register (cvt_pk) directly into the 16x16x16
// MFMA A-fragment layout -> no P LDS transpose. LDS = 32KB.
// NOTE lane ownership transpose: softmax stats (mrun/lrun/alpha) live on the
// lane with q=fr; the PV accumulator po holds q=4g+r -> alpha and 1/l must be
// re-broadcast via __shfl(_, 4g+r) before touching po. (R2 bug: missing this
// broadcast for alpha.)
// ---------------------------------------------------------------------------
__global__ __launch_bounds__(256, 3) void k_attn(
    const u16* __restrict__ Qg, const u16* __restrict__ Kg, const u16* __restrict__ Vtg,
    u16* __restrict__ headb)
{
  __shared__ u16 K_lds[128 * 64];     // 16KB
  __shared__ u16 V_lds[64 * 128];     // 16KB
  const int tid = threadIdx.x, lane = tid & 63, w = tid >> 6;
  const int fr = lane & 15, g = lane >> 4;
  const int qb = blockIdx.x, bh = blockIdx.y;
  const u16* Qbase = Qg + (size_t)bh * 2048 * 64;
  const u16* Kbase = Kg + (size_t)bh * 2048 * 64;
  const u16* Vbase = Vtg + (size_t)bh * 64 * 2048;

  // Q fragments (B-operand of swapped QK^T; pre-scaled by 0.125*log2e)
  short8 qf[2][2];
#pragma unroll
  for (int mi = 0; mi < 2; ++mi)
#pragma unroll
    for (int kt = 0; kt < 2; ++kt) {
      int qrow = qb * 128 + w * 32 + mi * 16 + fr;
      qf[mi][kt] = *(const short8*)&Qbase[(size_t)qrow * 64 + kt * 32 + g * 8];
    }

  f32x4 po[2][4];
  f32x4 z = {0.f, 0.f, 0.f, 0.f};
#pragma unroll
  for (int mi = 0; mi < 2; ++mi)
#pragma unroll
    for (int dt = 0; dt < 4; ++dt) po[mi][dt] = z;
  float mrun[2] = {-1e30f, -1e30f};
  float lrun[2] = {0.f, 0.f};

  for (int kv = 0; kv < 16; ++kv) {
    __syncthreads();
    // stage K tile [128][64] (16B-chunk XOR swizzle by row&7)
#pragma unroll
    for (int i = 0; i < 4; ++i) {
      int c = w * 4 + i;
      int row = c * 8 + (lane >> 3);
      int ci = lane & 7;
      gld16(Kbase + ((size_t)(kv * 128 + row)) * 64 + ((ci ^ (row & 7)) << 3), &K_lds[c * 512]);
    }
    // stage V^T tile [64][128] (16B-chunk XOR swizzle by row&7)
#pragma unroll
    for (int i = 0; i < 4; ++i) {
      int c = w * 4 + i;
      int row = c * 4 + (lane >> 4);
      int ci = lane & 15;
      gld16(Vbase + (size_t)row * 2048 + kv * 128 + ((ci ^ (row & 7)) << 3), &V_lds[c * 512]);
    }
    __syncthreads();

    // S^T = K Q^T : lane (fr,g) holds S[k = nt*16+4g+r][q = mi*16+fr]
    f32x4 sc[2][8];
#pragma unroll
    for (int mi = 0; mi < 2; ++mi)
#pragma unroll
      for (int nt = 0; nt < 8; ++nt) sc[mi][nt] = z;
#pragma unroll
    for (int nt = 0; nt < 8; ++nt) {
      int rk = nt * 16 + fr;
#pragma unroll
      for (int kt = 0; kt < 2; ++kt) {
        short8 kb = *(const short8*)&K_lds[rk * 64 + (((kt * 4 + g) ^ (rk & 7)) << 3)];
        sc[0][nt] = MFMA16(kb, qf[0][kt], sc[0][nt]);
        sc[1][nt] = MFMA16(kb, qf[1][kt], sc[1][nt]);
      }
    }

    // register-local online softmax + in-register P pack (A-frag of 16x16x16)
    short4b pa[2][8];
#pragma unroll
    for (int mi = 0; mi < 2; ++mi) {
      f32x4 m4 = sc[mi][0];
#pragma unroll
      for (int nt = 1; nt < 8; ++nt) m4 = v4max(m4, sc[mi][nt]);
      float mx = fmaxf(fmaxf(m4.x, m4.y), fmaxf(m4.z, m4.w));
      mx = fmaxf(mx, __shfl_xor(mx, 16, 64));
      mx = fmaxf(mx, __shfl_xor(mx, 32, 64));
      float mnew = fmaxf(mrun[mi], mx);
      float alpha = fexp2(mrun[mi] - mnew);
      f32x4 s4 = z;
#pragma unroll
      for (int nt = 0; nt < 8; ++nt) {
        f32x4 p;
        p.x = fexp2(sc[mi][nt].x - mnew);
        p.y = fexp2(sc[mi][nt].y - mnew);
        p.z = fexp2(sc[mi][nt].z - mnew);
        p.w = fexp2(sc[mi][nt].w - mnew);
        sc[mi][nt] = p;
        s4 += p;
      }
      float rs = (s4.x + s4.y) + (s4.z + s4.w);
      rs += __shfl_xor(rs, 16, 64);
      rs += __shfl_xor(rs, 32, 64);
      lrun[mi] = lrun[mi] * alpha + rs;
      mrun[mi] = mnew;
      // po holds q=4g+r: fetch each row's alpha from the lane that owns it (q=fr)
      f32x4 al4;
#pragma unroll
      for (int r = 0; r < 4; ++r) al4[r] = __shfl(alpha, 4 * g + r, 64);
#pragma unroll
      for (int dt = 0; dt < 4; ++dt) po[mi][dt] *= al4;
#pragma unroll
      for (int nt = 0; nt < 8; ++nt) {
        union { u32 u[2]; short4b s; } cv;
        cv.u[0] = cvtpk(sc[mi][nt].x, sc[mi][nt].y);
        cv.u[1] = cvtpk(sc[mi][nt].z, sc[mi][nt].w);
        pa[mi][nt] = cv.s;
      }
    }

    // O += P V via 16x16x16 MFMA (A = in-register P, B = V^T from LDS)
#pragma unroll
    for (int nt = 0; nt < 8; ++nt) {
#pragma unroll
      for (int dt = 0; dt < 4; ++dt) {
        int d = dt * 16 + fr;
        short4b vb = *(const short4b*)&V_lds[d * 128 + ((((nt << 1) | (g >> 1)) ^ (d & 7)) << 3) + ((g & 1) << 2)];
        po[0][dt] = mfma_k16(pa[0][nt], vb, po[0][dt]);
        po[1][dt] = mfma_k16(pa[1][nt], vb, po[1][dt]);
      }
    }
  }

  // epilogue: head[b][s][h*64+d] = O / l  (l lives on lane fr=q; rows on 4g+r)
  float linv[2][4];
#pragma unroll
  for (int mi = 0; mi < 2; ++mi)
#pragma unroll
    for (int r = 0; r < 4; ++r)
      linv[mi][r] = 1.0f / __shfl(lrun[mi], 4 * g + r, 64);

  const int b = bh >> 4, h = bh & 15;
#pragma unroll
  for (int mi = 0; mi < 2; ++mi)
#pragma unroll
    for (int dt = 0; dt < 4; ++dt)
#pragma unroll
      for (int r = 0; r < 4; ++r) {
        int srow = qb * 128 + w * 32 + mi * 16 + 4 * g + r;
        float v = po[mi][dt][r] * linv[mi][r];
        int e = h * 64 + dt * 16 + fr;
        headb[((size_t)(b * 2048 + srow)) * 1024 + e] = f2bf(v);
      }
}

// ---------------------------------------------------------------------------
// Output projection: proj = head @ Wo^T + bo  (bf16 out)
// ---------------------------------------------------------------------------
__global__ __launch_bounds__(256) void k_gemm_o(
    const u16* __restrict__ headb, const u16* __restrict__ wob, const float* __restrict__ bo,
    u16* __restrict__ projb)
{
  __shared__ u16 As[128 * 32], Bs[128 * 32];
  const int m0 = blockIdx.x * 128, n0 = blockIdx.y * 128;
  f32x4 acc[4][4];
  f32x4 z = {0.f, 0.f, 0.f, 0.f};
#pragma unroll
  for (int i = 0; i < 4; ++i)
#pragma unroll
    for (int j = 0; j < 4; ++j) acc[i][j] = z;

  gemm_mainloop(headb, wob, m0, n0, As, Bs, acc);

  const int tid = threadIdx.x, lane = tid & 63, w = tid >> 6;
  const int fr = lane & 15, g = lane >> 4;
  const int wm = w >> 1, wn = w & 1;
#pragma unroll
  for (int mi = 0; mi < 4; ++mi)
#pragma unroll
    for (int ni = 0; ni < 4; ++ni) {
      int n = n0 + wn * 64 + ni * 16 + fr;
      float bv_ = bo[n];
#pragma unroll
      for (int r = 0; r < 4; ++r) {
        int m = m0 + wm * 64 + mi * 16 + 4 * g + r;
        projb[(size_t)m * 1024 + n] = f2bf(acc[mi][ni][r] + bv_);
      }
    }
}

// ---------------------------------------------------------------------------
// LayerNorm + residual
// ---------------------------------------------------------------------------
__global__ __launch_bounds__(256) void k_ln(
    const u16* __restrict__ projb, const float* __restrict__ x,
    const float* __restrict__ gamma, const float* __restrict__ beta, float* __restrict__ out)
{
  __shared__ float sh1[4], sh2[4];
  const int row = blockIdx.x, t = threadIdx.x, lane = t & 63, w = t >> 6;
  const size_t base = (size_t)row * 1024;
  u16x4 pv = *(const u16x4*)&projb[base + t * 4];
  float v0 = bf2f(pv.x), v1 = bf2f(pv.y), v2 = bf2f(pv.z), v3 = bf2f(pv.w);
  float s1 = v0 + v1 + v2 + v3;
  float s2 = v0 * v0 + v1 * v1 + v2 * v2 + v3 * v3;
  for (int m = 1; m < 64; m <<= 1) {
    s1 += __shfl_xor(s1, m, 64);
    s2 += __shfl_xor(s2, m, 64);
  }
  if (lane == 0) { sh1[w] = s1; sh2[w] = s2; }
  __syncthreads();
  s1 = sh1[0] + sh1[1] + sh1[2] + sh1[3];
  s2 = sh2[0] + sh2[1] + sh2[2] + sh2[3];
  float mu = s1 * (1.0f / 1024.0f);
  float var = s2 * (1.0f / 1024.0f) - mu * mu;
  float rsd = rsqrtf(var + 1e-5f);
  f32x4 xv = *(const f32x4*)&x[base + t * 4];
  f32x4 res;
  int e = t * 4;
  res.x = xv.x + (v0 - mu) * rsd * gamma[e + 0] + beta[e + 0];
  res.y = xv.y + (v1 - mu) * rsd * gamma[e + 1] + beta[e + 1];
  res.z = xv.z + (v2 - mu) * rsd * gamma[e + 2] + beta[e + 2];
  res.w = xv.w + (v3 - mu) * rsd * gamma[e + 3] + beta[e + 3];
  *(f32x4*)&out[base + t * 4] = res;
}

// ---------------------------------------------------------------------------
extern "C" void kernel_launch(void* const* d_in, const int* in_sizes, int n_in,
                              void* d_out, int out_size, void* d_ws, size_t ws_size,
                              hipStream_t stream)
{
  const float* x     = (const float*)d_in[0];
  const float* Wq    = (const float*)d_in[1];
  const float* bq    = (const float*)d_in[2];
  const float* Wk    = (const float*)d_in[3];
  const float* bk    = (const float*)d_in[4];
  const float* Wv    = (const float*)d_in[5];
  const float* bv    = (const float*)d_in[6];
  const float* Wo    = (const float*)d_in[7];
  const float* bo    = (const float*)d_in[8];
  const float* gamma = (const float*)d_in[9];
  const float* beta  = (const float*)d_in[10];
  float* out = (float*)d_out;

  u16* ws   = (u16*)d_ws;
  u16* xb   = ws;                    // 8192*1024
  u16* wqb  = ws + 8388608;
  u16* wkb  = wqb + 1048576;
  u16* wvb  = wkb + 1048576;
  u16* wob  = wvb + 1048576;
  u16* Qg   = wob + 1048576;         // [64][2048][64]
  u16* Kg   = Qg + 8388608;          // [64][2048][64]
  u16* Vtg  = Kg + 8388608;          // [64][64][2048]
  u16* headb = Vtg + 8388608;        // [8192][1024]
  u16* projb = Qg;                   // reuse Q region (dead after attention)

  k_convert<<<12288, 256, 0, stream>>>(x, Wq, Wk, Wv, Wo, ws);
  k_gemm_qkv<<<dim3(64, 24), 256, 0, stream>>>(xb, wqb, wkb, wvb, bq, bk, bv, Qg, Kg, Vtg);
  k_attn<<<dim3(16, 64), 256, 0, stream>>>(Qg, Kg, Vtg, headb);
  k_gemm_o<<<dim3(64, 8), 256, 0, stream>>>(headb, wob, bo, projb);
  k_ln<<<8192, 256, 0, stream>>>(projb, x, gamma, beta, out);
}